// Round 11
// baseline (589.970 us; speedup 1.0000x reference)
//
#include <hip/hip_runtime.h>
#include <hip/hip_cooperative_groups.h>

namespace cg = cooperative_groups;

#define D 128
#define FILLV 0.5f
#define NXCD 8
#define EPT 8    // edges per thread in cnt

// Packed u32 bucket counter: count in bits[22:31], degree w*2^16 in bits[0:21].
// cnt floor established (r4/r6/r7/r9): device-scope RMW point retires ~22G op/s,
// per-op bound (layout/MLP/width/scope-insensitive). 1.6M returned RMWs irreducible.
#define CNT_SHIFT 22
#define DEG_MASK  0x3FFFFFu

typedef unsigned short u16;
typedef unsigned long long u64;
typedef unsigned uv4 __attribute__((ext_vector_type(4)));   // 16B nontemporal
typedef u64 u64v2 __attribute__((ext_vector_type(2)));      // 16B nontemporal

__device__ __forceinline__ u16 f2bf(float f) {          // RNE fp32 -> bf16
    unsigned u = __float_as_uint(f);
    u += 0x7FFF + ((u >> 16) & 1);
    return (u16)(u >> 16);
}
__device__ __forceinline__ float bf2f(u16 h) {
    return __uint_as_float(((unsigned)h) << 16);
}

// ---------------------------------------------------------------------------
// FUSED pass 1 (r7, at its atomic floor): edge blocks issue 2*EPT independent
// packed u32 atomics; returns give within-bucket ranks (u16x2). Conversion
// blocks stream fp32->bf16 staging under the atomic latency.
__global__ void cnt_tobf_kernel(const int* __restrict__ row, const int* __restrict__ col,
                                const float* __restrict__ w,
                                unsigned* __restrict__ cnt32, unsigned* __restrict__ ranks,
                                const float* __restrict__ x_s, const float* __restrict__ x_t,
                                u16* __restrict__ xb_s, u16* __restrict__ xb_t,
                                int E, int N, int nEB, long long nd) {
    if ((int)blockIdx.x < nEB) {
        long long g  = (long long)blockIdx.x * 256 + threadIdx.x;
        long long e0 = g * EPT;
        if (e0 >= E) return;
        if (e0 + EPT <= E && (E & 3) == 0) {
            int rr[EPT]; int cc[EPT]; unsigned fx[EPT];
            #pragma unroll
            for (int h = 0; h < EPT / 4; ++h) {
                int q = (int)(e0 >> 2) + h;
                int4   r4 = *(const int4*)(row + 4 * (size_t)q);
                int4   c4 = *(const int4*)(col + 4 * (size_t)q);
                float4 w4 = *(const float4*)(w + 4 * (size_t)q);
                rr[4*h] = r4.x; rr[4*h+1] = r4.y; rr[4*h+2] = r4.z; rr[4*h+3] = r4.w;
                cc[4*h] = c4.x; cc[4*h+1] = c4.y; cc[4*h+2] = c4.z; cc[4*h+3] = c4.w;
                fx[4*h]   = (unsigned)(w4.x * 65536.0f);
                fx[4*h+1] = (unsigned)(w4.y * 65536.0f);
                fx[4*h+2] = (unsigned)(w4.z * 65536.0f);
                fx[4*h+3] = (unsigned)(w4.w * 65536.0f);
            }
            unsigned oc[EPT], orr[EPT];
            #pragma unroll
            for (int k = 0; k < EPT; ++k) {
                unsigned add = (1u << CNT_SHIFT) | fx[k];
                oc[k]  = atomicAdd(&cnt32[(size_t)cc[k]], add);
                orr[k] = atomicAdd(&cnt32[(size_t)N + rr[k]], add);
            }
            unsigned pk[EPT];
            #pragma unroll
            for (int k = 0; k < EPT; ++k)
                pk[k] = ((orr[k] >> CNT_SHIFT) << 16) | (oc[k] >> CNT_SHIFT);
            uv4 pa = {pk[0], pk[1], pk[2], pk[3]};
            uv4 pb = {pk[4], pk[5], pk[6], pk[7]};
            __builtin_nontemporal_store(pa, (uv4*)(ranks + e0));
            __builtin_nontemporal_store(pb, (uv4*)(ranks + e0 + 4));
        } else {
            for (long long e = e0; e < E && e < e0 + EPT; ++e) {
                int r = row[e], c = col[e];
                unsigned add = (1u << CNT_SHIFT) | (unsigned)(w[e] * 65536.0f);
                unsigned oc  = atomicAdd(&cnt32[(size_t)c], add);
                unsigned orr = atomicAdd(&cnt32[(size_t)N + r], add);
                ranks[e] = ((orr >> CNT_SHIFT) << 16) | (oc >> CNT_SHIFT);
            }
        }
    } else {
        long long t = (long long)(blockIdx.x - nEB) * 256 + threadIdx.x;
        long long q = nd / 4;
        const float* x; u16* xb; long long i;
        if (t < q) { x = x_s; xb = xb_s; i = t * 4; }
        else if (t < 2 * q) { x = x_t; xb = xb_t; i = (t - q) * 4; }
        else return;
        float4 v = *(const float4*)(x + i);
        ushort4 o;
        o.x = f2bf(v.x); o.y = f2bf(v.y); o.z = f2bf(v.z); o.w = f2bf(v.w);
        *(ushort4*)(xb + i) = o;
    }
}

// ---------------------------------------------------------------------------
// COOPERATIVE mid kernel: fuses {scanAI, scanC, slot2, fill2} with
// grid.sync() between phases — cuts 3 dispatch boundaries (~9us each, r10
// budget analysis). Grid = ceil(E/1024) = slot2's natural size (one 1024-edge
// chunk per block); P1/P2/P4 grid-stride. Phase bodies identical to r10.
__global__ void mid_kernel(unsigned* __restrict__ cnt32, float* __restrict__ dinv,
                           int* __restrict__ tsum, int* __restrict__ start,
                           const int* __restrict__ row, const int* __restrict__ col,
                           const float* __restrict__ w, const unsigned* __restrict__ ranks,
                           unsigned* __restrict__ cursor,
                           unsigned* __restrict__ bslot, u64* __restrict__ bpay,
                           u64* __restrict__ edges,
                           int E, int N, int SL, int nTiles, int total, int grand_total) {
    __shared__ int sh[256];
    __shared__ unsigned hist[NXCD];
    __shared__ unsigned wbase[NXCD];
    cg::grid_group grid = cg::this_grid();
    const int tid = threadIdx.x;

    // ---- P1 (scanAI): unpack counter -> dinv + plain count; per-tile reduce.
    for (int tile = blockIdx.x; tile < nTiles; tile += gridDim.x) {
        int gid = tile * 256 + tid;
        int cnt = 0;
        if (gid < total) {
            unsigned v = cnt32[gid];
            float deg = (float)(v & DEG_MASK) * (1.0f / 65536.0f);
            dinv[gid] = 1.0f / (deg + FILLV);
            cnt = (int)(v >> CNT_SHIFT);
            cnt32[gid] = (unsigned)cnt;
        }
        sh[tid] = cnt;
        __syncthreads();
        for (int off = 128; off > 0; off >>= 1) {
            if (tid < off) sh[tid] += sh[tid + off];
            __syncthreads();
        }
        if (tid == 0) tsum[tile] = sh[0];
        __syncthreads();
    }
    grid.sync();

    // ---- P2 (scanC): per-block tsum-prefix reduce + intra-block scan.
    for (int tile = blockIdx.x; tile < nTiles; tile += gridDim.x) {
        int acc = 0;
        for (int j = tid; j < tile; j += 256) acc += tsum[j];
        sh[tid] = acc;
        __syncthreads();
        for (int off = 128; off > 0; off >>= 1) {
            if (tid < off) sh[tid] += sh[tid + off];
            __syncthreads();
        }
        int bpref = sh[0];
        __syncthreads();
        int gid = tile * 256 + tid;
        int v = (gid < total) ? (int)cnt32[gid] : 0;
        sh[tid] = v;
        __syncthreads();
        for (int off = 1; off < 256; off <<= 1) {
            int u = 0;
            if (tid >= off) u = sh[tid - off];
            __syncthreads();
            sh[tid] += u;
            __syncthreads();
        }
        int run = bpref + sh[tid] - v;   // exclusive
        if (gid < total) start[gid] = run;
        if (gid == 0) start[total] = grand_total;
        __syncthreads();
    }
    grid.sync();

    // ---- P3 (slot2): compute records once, bin by slot-range via LDS hist
    // + 8 global cursor atomics/WG. One 1024-edge chunk per block (grid sized).
    {
        if (tid < NXCD) hist[tid] = 0;
        __syncthreads();
        long long g  = (long long)blockIdx.x * 256 + tid;
        long long e0 = g * 4;
        unsigned rslot[8]; u64 rpay[8]; unsigned rbin[8], rrank[8];
        int nrec = 0;
        if (e0 < E) {
            if (e0 + 4 <= E && (E & 3) == 0) {
                int q = (int)(e0 >> 2);
                int4   r4 = *(const int4*)(row + 4 * (size_t)q);
                int4   c4 = *(const int4*)(col + 4 * (size_t)q);
                float4 w4 = *(const float4*)(w + 4 * (size_t)q);
                uv4    p4 = __builtin_nontemporal_load((const uv4*)(ranks + e0));
                int rr[4] = {r4.x, r4.y, r4.z, r4.w};
                int cc[4] = {c4.x, c4.y, c4.z, c4.w};
                float ww[4] = {w4.x, w4.y, w4.z, w4.w};
                unsigned pk[4] = {p4.x, p4.y, p4.z, p4.w};
                #pragma unroll
                for (int k = 0; k < 4; ++k) {
                    int ss = start[cc[k]] + (int)(pk[k] & 0xffffu);
                    int st = start[N + rr[k]] + (int)(pk[k] >> 16);
                    float wns = ww[k] * dinv[N + rr[k]];
                    float wnt = ww[k] * dinv[cc[k]];
                    rslot[nrec] = (unsigned)ss;
                    rpay[nrec]  = ((u64)__float_as_uint(wns) << 32) | (unsigned)rr[k];
                    ++nrec;
                    rslot[nrec] = (unsigned)st;
                    rpay[nrec]  = ((u64)__float_as_uint(wnt) << 32) | (unsigned)cc[k];
                    ++nrec;
                }
            } else {
                for (long long e = e0; e < E && e < e0 + 4; ++e) {
                    int r = row[e], c = col[e];
                    float we = w[e];
                    unsigned pk = ranks[e];
                    int ss = start[c] + (int)(pk & 0xffffu);
                    int st = start[N + r] + (int)(pk >> 16);
                    float wns = we * dinv[N + r];
                    float wnt = we * dinv[c];
                    rslot[nrec] = (unsigned)ss;
                    rpay[nrec]  = ((u64)__float_as_uint(wns) << 32) | (unsigned)r;
                    ++nrec;
                    rslot[nrec] = (unsigned)st;
                    rpay[nrec]  = ((u64)__float_as_uint(wnt) << 32) | (unsigned)c;
                    ++nrec;
                }
            }
            for (int j = 0; j < nrec; ++j) {
                rbin[j]  = rslot[j] / (unsigned)SL;
                rrank[j] = atomicAdd(&hist[rbin[j]], 1u);
            }
        }
        __syncthreads();
        if (tid < NXCD)
            wbase[tid] = atomicAdd(&cursor[tid], hist[tid]);
        __syncthreads();
        for (int j = 0; j < nrec; ++j) {
            unsigned pos = rbin[j] * (unsigned)SL + wbase[rbin[j]] + rrank[j];
            bslot[pos] = rslot[j];
            bpay[pos]  = rpay[j];
        }
    }
    grid.sync();

    // ---- P4 (fill2): bin rid read sequentially exactly once, scattered into
    // its own slot window. rid FIXED per block (blockIdx&7) so the XCD-range
    // L2 write-merge property is preserved; chunk-strides within the bin.
    {
        int g8 = (int)(gridDim.x >> 3);
        if ((int)blockIdx.x < (g8 << 3)) {
            int rid = blockIdx.x & 7;
            int nchunk = (SL + 511) / 512;
            long long lo  = (long long)rid * SL;
            long long rem = (long long)(2 * E) - lo;
            int cntb = rem < 0 ? 0 : (rem > SL ? SL : (int)rem);
            for (int chunk = blockIdx.x >> 3; chunk < nchunk; chunk += g8) {
                long long idx = ((long long)chunk * 256 + tid) * 2;
                if (idx >= cntb) continue;
                long long p = lo + idx;
                if (idx + 2 <= cntb) {
                    u64   s2 = __builtin_nontemporal_load((const u64*)(bslot + p));
                    u64v2 y2 = __builtin_nontemporal_load((const u64v2*)(bpay + p));
                    edges[(unsigned)(s2 & 0xffffffffu)] = y2[0];
                    edges[(unsigned)(s2 >> 32)] = y2[1];
                } else {
                    edges[bslot[p]] = __builtin_nontemporal_load(bpay + p);
                }
            }
        }
    }
}

// ---------------------------------------------------------------------------
// Pull kernels (r7 half-wave, best measured): wave per bucket; HALF-WAVE per
// edge (bf16 row = 256B = 32 lanes x ushort4). Main loop 8 edges/iter.
__global__ void pull1_kernel(const int* __restrict__ start, const int2* __restrict__ edges,
                             const float* __restrict__ dinv,
                             const u16* __restrict__ xb_s, const u16* __restrict__ xb_t,
                             const float* __restrict__ x_s, const float* __restrict__ x_t,
                             u16* __restrict__ ab_s, u16* __restrict__ ab_t, int N) {
    int wid0 = (int)(((long long)blockIdx.x * blockDim.x + threadIdx.x) >> 6);
    int wid = __builtin_amdgcn_readfirstlane(wid0);
    int lane = threadIdx.x & 63;
    int half = lane >> 5, hl = lane & 31;
    if (wid >= 2 * N) return;
    const u16* xb; const float* x; u16* ab; int i, o;
    if (wid < N) { i = wid;     o = N; xb = xb_s; x = x_s; ab = ab_s; }
    else         { i = wid - N; o = 0; xb = xb_t; x = x_t; ab = ab_t; }
    int s0 = start[wid], s1 = start[wid + 1];
    float a0 = 0.f, a1 = 0.f, a2 = 0.f, a3 = 0.f;
    int k = s0;
    for (; k + 8 <= s1; k += 8) {
        int b = k + 4 * half;
        int2 p0 = edges[b], p1 = edges[b + 1], p2 = edges[b + 2], p3 = edges[b + 3];
        ushort4 v0 = *(const ushort4*)(xb + (size_t)p0.x * D + hl * 4);
        ushort4 v1 = *(const ushort4*)(xb + (size_t)p1.x * D + hl * 4);
        ushort4 v2 = *(const ushort4*)(xb + (size_t)p2.x * D + hl * 4);
        ushort4 v3 = *(const ushort4*)(xb + (size_t)p3.x * D + hl * 4);
        float w0v = __int_as_float(p0.y), w1v = __int_as_float(p1.y);
        float w2v = __int_as_float(p2.y), w3v = __int_as_float(p3.y);
        a0 += w0v * bf2f(v0.x) + w1v * bf2f(v1.x) + w2v * bf2f(v2.x) + w3v * bf2f(v3.x);
        a1 += w0v * bf2f(v0.y) + w1v * bf2f(v1.y) + w2v * bf2f(v2.y) + w3v * bf2f(v3.y);
        a2 += w0v * bf2f(v0.z) + w1v * bf2f(v1.z) + w2v * bf2f(v2.z) + w3v * bf2f(v3.z);
        a3 += w0v * bf2f(v0.w) + w1v * bf2f(v1.w) + w2v * bf2f(v2.w) + w3v * bf2f(v3.w);
    }
    if (k + 4 <= s1) {
        int b = k + 2 * half;
        int2 p0 = edges[b], p1 = edges[b + 1];
        ushort4 v0 = *(const ushort4*)(xb + (size_t)p0.x * D + hl * 4);
        ushort4 v1 = *(const ushort4*)(xb + (size_t)p1.x * D + hl * 4);
        float w0v = __int_as_float(p0.y), w1v = __int_as_float(p1.y);
        a0 += w0v * bf2f(v0.x) + w1v * bf2f(v1.x);
        a1 += w0v * bf2f(v0.y) + w1v * bf2f(v1.y);
        a2 += w0v * bf2f(v0.z) + w1v * bf2f(v1.z);
        a3 += w0v * bf2f(v0.w) + w1v * bf2f(v1.w);
        k += 4;
    }
    for (; k < s1; ++k) {
        if (half == 0) {
            int2 p = edges[k];
            ushort4 v = *(const ushort4*)(xb + (size_t)p.x * D + hl * 4);
            float wv = __int_as_float(p.y);
            a0 += wv * bf2f(v.x); a1 += wv * bf2f(v.y);
            a2 += wv * bf2f(v.z); a3 += wv * bf2f(v.w);
        }
    }
    a0 += __shfl_xor(a0, 32); a1 += __shfl_xor(a1, 32);
    a2 += __shfl_xor(a2, 32); a3 += __shfl_xor(a3, 32);
    if (half == 0) {
        float sw = FILLV * dinv[o + i];
        float4 xv = *(const float4*)(x + (size_t)i * D + hl * 4);
        a0 += sw * xv.x; a1 += sw * xv.y; a2 += sw * xv.z; a3 += sw * xv.w;
        ushort4 ov;
        ov.x = f2bf(a0); ov.y = f2bf(a1); ov.z = f2bf(a2); ov.w = f2bf(a3);
        *(ushort4*)(ab + (size_t)i * D + hl * 4) = ov;
    }
}

// Hop-2 pull + fused epilogue: out_half = w0*x + w1*a + w2*(conv(a)).
__global__ void pull2_kernel(const int* __restrict__ start, const int2* __restrict__ edges,
                             const float* __restrict__ dinv,
                             const u16* __restrict__ ab_s, const u16* __restrict__ ab_t,
                             const float* __restrict__ x_s, const float* __restrict__ x_t,
                             float* __restrict__ out,
                             const float* __restrict__ w_s, const float* __restrict__ w_t, int N) {
    int wid0 = (int)(((long long)blockIdx.x * blockDim.x + threadIdx.x) >> 6);
    int wid = __builtin_amdgcn_readfirstlane(wid0);
    int lane = threadIdx.x & 63;
    int half = lane >> 5, hl = lane & 31;
    if (wid >= 2 * N) return;
    const u16* ab; const float* x; const float* wv3; int i, o, hoff;
    if (wid < N) { i = wid;     o = N; ab = ab_s; x = x_s; wv3 = w_s; hoff = 0; }
    else         { i = wid - N; o = 0; ab = ab_t; x = x_t; wv3 = w_t; hoff = D; }
    int s0 = start[wid], s1 = start[wid + 1];
    float a0 = 0.f, a1 = 0.f, a2 = 0.f, a3 = 0.f;
    int k = s0;
    for (; k + 8 <= s1; k += 8) {
        int b = k + 4 * half;
        int2 p0 = edges[b], p1 = edges[b + 1], p2 = edges[b + 2], p3 = edges[b + 3];
        ushort4 v0 = *(const ushort4*)(ab + (size_t)p0.x * D + hl * 4);
        ushort4 v1 = *(const ushort4*)(ab + (size_t)p1.x * D + hl * 4);
        ushort4 v2 = *(const ushort4*)(ab + (size_t)p2.x * D + hl * 4);
        ushort4 v3 = *(const ushort4*)(ab + (size_t)p3.x * D + hl * 4);
        float w0v = __int_as_float(p0.y), w1v = __int_as_float(p1.y);
        float w2v = __int_as_float(p2.y), w3v = __int_as_float(p3.y);
        a0 += w0v * bf2f(v0.x) + w1v * bf2f(v1.x) + w2v * bf2f(v2.x) + w3v * bf2f(v3.x);
        a1 += w0v * bf2f(v0.y) + w1v * bf2f(v1.y) + w2v * bf2f(v2.y) + w3v * bf2f(v3.y);
        a2 += w0v * bf2f(v0.z) + w1v * bf2f(v1.z) + w2v * bf2f(v2.z) + w3v * bf2f(v3.z);
        a3 += w0v * bf2f(v0.w) + w1v * bf2f(v1.w) + w2v * bf2f(v2.w) + w3v * bf2f(v3.w);
    }
    if (k + 4 <= s1) {
        int b = k + 2 * half;
        int2 p0 = edges[b], p1 = edges[b + 1];
        ushort4 v0 = *(const ushort4*)(ab + (size_t)p0.x * D + hl * 4);
        ushort4 v1 = *(const ushort4*)(ab + (size_t)p1.x * D + hl * 4);
        float w0v = __int_as_float(p0.y), w1v = __int_as_float(p1.y);
        a0 += w0v * bf2f(v0.x) + w1v * bf2f(v1.x);
        a1 += w0v * bf2f(v0.y) + w1v * bf2f(v1.y);
        a2 += w0v * bf2f(v0.z) + w1v * bf2f(v1.z);
        a3 += w0v * bf2f(v0.w) + w1v * bf2f(v1.w);
        k += 4;
    }
    for (; k < s1; ++k) {
        if (half == 0) {
            int2 p = edges[k];
            ushort4 v = *(const ushort4*)(ab + (size_t)p.x * D + hl * 4);
            float wv = __int_as_float(p.y);
            a0 += wv * bf2f(v.x); a1 += wv * bf2f(v.y);
            a2 += wv * bf2f(v.z); a3 += wv * bf2f(v.w);
        }
    }
    a0 += __shfl_xor(a0, 32); a1 += __shfl_xor(a1, 32);
    a2 += __shfl_xor(a2, 32); a3 += __shfl_xor(a3, 32);
    if (half == 0) {
        float sw = FILLV * dinv[o + i];
        ushort4 av = *(const ushort4*)(ab + (size_t)i * D + hl * 4);
        float b0 = bf2f(av.x), b1 = bf2f(av.y), b2 = bf2f(av.z), b3 = bf2f(av.w);
        a0 += sw * b0; a1 += sw * b1; a2 += sw * b2; a3 += sw * b3;
        float w0 = wv3[0], w1 = wv3[1], w2 = wv3[2];
        float4 xv = *(const float4*)(x + (size_t)i * D + hl * 4);
        float4 ov;
        ov.x = w0 * xv.x + w1 * b0 + w2 * a0;
        ov.y = w0 * xv.y + w1 * b1 + w2 * a1;
        ov.z = w0 * xv.z + w1 * b2 + w2 * a2;
        ov.w = w0 * xv.w + w1 * b3 + w2 * a3;
        *(float4*)(out + (size_t)i * 2 * D + hoff + hl * 4) = ov;
    }
}

// ---------------------------------------------------------------------------
extern "C" void kernel_launch(void* const* d_in, const int* in_sizes, int n_in,
                              void* d_out, int out_size, void* d_ws, size_t ws_size,
                              hipStream_t stream) {
    const float* x_s = (const float*)d_in[0];
    const float* x_t = (const float*)d_in[1];
    const int*   ei  = (const int*)d_in[2];
    const float* ew  = (const float*)d_in[3];
    const float* w_s = (const float*)d_in[4];
    const float* w_t = (const float*)d_in[5];
    const int N = in_sizes[0] / D;
    const int E = in_sizes[3];
    const int* row = ei;
    const int* col = ei + E;

    const int total = 2 * N;
    const int nTiles = (total + 255) / 256;
    const int SL = ((2 * E + NXCD - 1) / NXCD + 7) & ~7;   // bin/range size

    // Workspace (d_ws): [dinv 2N][start 2N+2][tsum 512][align]
    // [edges 2E int2 (64B-aligned)] [xb_s ND u16][xb_t ND u16][ab_s][ab_t]
    // cnt32 (2N u32) + cursor (8 u32) alias ab_s: dead before pull1.
    float* f      = (float*)d_ws;
    float* dinv   = f;                              // 2N
    int*   start  = (int*)(f + (size_t)total);      // 2N+2
    int*   tsum   = start + (total + 2);            // 512
    char*  pc     = (char*)(tsum + 512);
    pc = (char*)(((size_t)pc + 255) & ~(size_t)255);
    u64*   edges  = (u64*)pc;                       // 2E int2, 64B-aligned
    u16*   xb_s   = (u16*)(edges + 2 * (size_t)E);
    u16*   xb_t   = xb_s + (size_t)N * D;
    u16*   ab_s   = xb_t + (size_t)N * D;
    u16*   ab_t   = ab_s + (size_t)N * D;
    unsigned* cnt32  = (unsigned*)ab_s;             // 2N, dead before pull1
    unsigned* cursor = cnt32 + (size_t)total;       // 8 bin cursors

    // d_out scratch (dead until pull2 writes): ranks u32[E], then binned
    // records bslot u32[8SL] + bpay u64[8SL] (16B-aligned). ~22.4MB total.
    unsigned* ranks = (unsigned*)d_out;
    char* po = (char*)d_out + (((size_t)E * 4 + 15) & ~(size_t)15);
    unsigned* bslot = (unsigned*)po;                           // 8SL u32
    u64*      bpay  = (u64*)(bslot + (size_t)NXCD * SL);       // 8SL u64
    float* out = (float*)d_out;

    hipMemsetAsync(cnt32, 0, ((size_t)total + NXCD) * sizeof(unsigned), stream);

    long long nd = (long long)N * D;
    int blkC = (int)((nd / 2 + 255) / 256);
    int nEB  = (E + EPT * 256 - 1) / (EPT * 256);
    cnt_tobf_kernel<<<nEB + blkC, 256, 0, stream>>>(row, col, ew, cnt32, ranks,
                                                    x_s, x_t, xb_s, xb_t,
                                                    E, N, nEB, nd);

    // Cooperative mid kernel: scanAI+scanC+slot2+fill2 with grid syncs.
    const int blkMid = (E + 1023) / 1024;           // slot2's natural grid
    const int grand_total = 2 * E;
    void* margs[] = {(void*)&cnt32, (void*)&dinv, (void*)&tsum, (void*)&start,
                     (void*)&row, (void*)&col, (void*)&ew, (void*)&ranks,
                     (void*)&cursor, (void*)&bslot, (void*)&bpay, (void*)&edges,
                     (void*)&E, (void*)&N, (void*)&SL, (void*)&nTiles,
                     (void*)&total, (void*)&grand_total};
    hipLaunchCooperativeKernel((void*)mid_kernel, dim3(blkMid), dim3(256),
                               margs, 0, stream);

    long long pull_threads = (long long)total * 64;
    int blkP = (int)((pull_threads + 255) / 256);
    pull1_kernel<<<blkP, 256, 0, stream>>>(start, (const int2*)edges, dinv, xb_s, xb_t,
                                           x_s, x_t, ab_s, ab_t, N);
    pull2_kernel<<<blkP, 256, 0, stream>>>(start, (const int2*)edges, dinv, ab_s, ab_t,
                                           x_s, x_t, out, w_s, w_t, N);
}

// Round 12
// 354.701 us; speedup vs baseline: 1.6633x; 1.6633x over previous
//
#include <hip/hip_runtime.h>

#define D 128
#define FILLV 0.5f
#define NXCD 8
#define EPT 8    // edges per thread in cnt

// Packed u32 bucket counter: count in bits[22:31], degree w*2^16 in bits[0:21].
// cnt floor established (r4/r6/r7/r9): device-scope RMW point retires ~22G op/s,
// per-op bound (layout/MLP/width/scope-insensitive). 1.6M returned RMWs irreducible.
// r11 lesson: cg::grid.sync() costs ~74us/sync on MI355X (8-XCD barrier) — banned.
#define CNT_SHIFT 22
#define DEG_MASK  0x3FFFFFu

typedef unsigned short u16;
typedef unsigned long long u64;
typedef unsigned uv4 __attribute__((ext_vector_type(4)));   // 16B nontemporal
typedef u64 u64v2 __attribute__((ext_vector_type(2)));      // 16B nontemporal

__device__ __forceinline__ u16 f2bf(float f) {          // RNE fp32 -> bf16
    unsigned u = __float_as_uint(f);
    u += 0x7FFF + ((u >> 16) & 1);
    return (u16)(u >> 16);
}
__device__ __forceinline__ float bf2f(u16 h) {
    return __uint_as_float(((unsigned)h) << 16);
}

// ---------------------------------------------------------------------------
// FUSED pass 1 (r7, at its atomic floor): edge blocks issue 2*EPT independent
// packed u32 atomics; returns give within-bucket ranks (u16x2). Conversion
// blocks stream fp32->bf16 staging under the atomic latency.
__global__ void cnt_tobf_kernel(const int* __restrict__ row, const int* __restrict__ col,
                                const float* __restrict__ w,
                                unsigned* __restrict__ cnt32, unsigned* __restrict__ ranks,
                                const float* __restrict__ x_s, const float* __restrict__ x_t,
                                u16* __restrict__ xb_s, u16* __restrict__ xb_t,
                                int E, int N, int nEB, long long nd) {
    if ((int)blockIdx.x < nEB) {
        long long g  = (long long)blockIdx.x * 256 + threadIdx.x;
        long long e0 = g * EPT;
        if (e0 >= E) return;
        if (e0 + EPT <= E && (E & 3) == 0) {
            int rr[EPT]; int cc[EPT]; unsigned fx[EPT];
            #pragma unroll
            for (int h = 0; h < EPT / 4; ++h) {
                int q = (int)(e0 >> 2) + h;
                int4   r4 = *(const int4*)(row + 4 * (size_t)q);
                int4   c4 = *(const int4*)(col + 4 * (size_t)q);
                float4 w4 = *(const float4*)(w + 4 * (size_t)q);
                rr[4*h] = r4.x; rr[4*h+1] = r4.y; rr[4*h+2] = r4.z; rr[4*h+3] = r4.w;
                cc[4*h] = c4.x; cc[4*h+1] = c4.y; cc[4*h+2] = c4.z; cc[4*h+3] = c4.w;
                fx[4*h]   = (unsigned)(w4.x * 65536.0f);
                fx[4*h+1] = (unsigned)(w4.y * 65536.0f);
                fx[4*h+2] = (unsigned)(w4.z * 65536.0f);
                fx[4*h+3] = (unsigned)(w4.w * 65536.0f);
            }
            unsigned oc[EPT], orr[EPT];
            #pragma unroll
            for (int k = 0; k < EPT; ++k) {
                unsigned add = (1u << CNT_SHIFT) | fx[k];
                oc[k]  = atomicAdd(&cnt32[(size_t)cc[k]], add);
                orr[k] = atomicAdd(&cnt32[(size_t)N + rr[k]], add);
            }
            unsigned pk[EPT];
            #pragma unroll
            for (int k = 0; k < EPT; ++k)
                pk[k] = ((orr[k] >> CNT_SHIFT) << 16) | (oc[k] >> CNT_SHIFT);
            uv4 pa = {pk[0], pk[1], pk[2], pk[3]};
            uv4 pb = {pk[4], pk[5], pk[6], pk[7]};
            __builtin_nontemporal_store(pa, (uv4*)(ranks + e0));
            __builtin_nontemporal_store(pb, (uv4*)(ranks + e0 + 4));
        } else {
            for (long long e = e0; e < E && e < e0 + EPT; ++e) {
                int r = row[e], c = col[e];
                unsigned add = (1u << CNT_SHIFT) | (unsigned)(w[e] * 65536.0f);
                unsigned oc  = atomicAdd(&cnt32[(size_t)c], add);
                unsigned orr = atomicAdd(&cnt32[(size_t)N + r], add);
                ranks[e] = ((orr >> CNT_SHIFT) << 16) | (oc >> CNT_SHIFT);
            }
        }
    } else {
        long long t = (long long)(blockIdx.x - nEB) * 256 + threadIdx.x;
        long long q = nd / 4;
        const float* x; u16* xb; long long i;
        if (t < q) { x = x_s; xb = xb_s; i = t * 4; }
        else if (t < 2 * q) { x = x_t; xb = xb_t; i = (t - q) * 4; }
        else return;
        float4 v = *(const float4*)(x + i);
        ushort4 o;
        o.x = f2bf(v.x); o.y = f2bf(v.y); o.z = f2bf(v.z); o.w = f2bf(v.w);
        *(ushort4*)(xb + i) = o;
    }
}

// ---------------------------------------------------------------------------
// Single-pass fused scan (replaces scanAI+scanC, one fewer dispatch):
// decoupled lookback. Each tile-block: unpack counter -> dinv; intra-block
// inclusive scan; publish (aggregate,flag=1) [tile 0 publishes flag=2];
// wave-0 does WAVE-PARALLEL lookback (64 predecessors per dependent round,
// <=7 rounds for 391 tiles) to get its exclusive prefix; publish inclusive
// (flag=2); write start[]. Safe: blocks dispatch in ascending order and all
// 391 are co-resident; block k only waits on j<k. Device-scope release/
// acquire atomics for cross-XCD visibility (local cost, unlike grid.sync).
__global__ void scanF_kernel(const unsigned* __restrict__ cnt32, float* __restrict__ dinv,
                             u64* __restrict__ tstate, int* __restrict__ start,
                             int total, int grand_total) {
    __shared__ int sh[256];
    __shared__ int s_prefix;
    const int tile = blockIdx.x;
    const int tid  = threadIdx.x;
    int gid = tile * 256 + tid;
    int cnt = 0;
    if (gid < total) {
        unsigned v = cnt32[gid];
        float deg = (float)(v & DEG_MASK) * (1.0f / 65536.0f);
        dinv[gid] = 1.0f / (deg + FILLV);
        cnt = (int)(v >> CNT_SHIFT);
    }
    int orig = cnt;
    sh[tid] = cnt;
    __syncthreads();
    for (int off = 1; off < 256; off <<= 1) {       // inclusive Hillis-Steele
        int u = 0;
        if (tid >= off) u = sh[tid - off];
        __syncthreads();
        sh[tid] += u;
        __syncthreads();
    }
    int incl = sh[tid];
    int local_total = sh[255];
    // publish aggregate ASAP (tile 0's aggregate IS its inclusive prefix)
    if (tid == 0) {
        u64 pub = ((u64)(unsigned)local_total << 32) | (tile == 0 ? 2u : 1u);
        __hip_atomic_store(&tstate[tile], pub, __ATOMIC_RELEASE, __HIP_MEMORY_SCOPE_AGENT);
        if (tile == 0) s_prefix = 0;
    }
    if (tile > 0 && tid < 64) {                     // wave-parallel lookback
        int prefix = 0;
        int j = tile - 1;
        for (;;) {
            int idx = j - tid;
            u64 st = 0;
            if (idx >= 0)
                st = __hip_atomic_load(&tstate[idx], __ATOMIC_ACQUIRE, __HIP_MEMORY_SCOPE_AGENT);
            unsigned flag = (unsigned)(st & 3u);
            u64 ball_valid = __ballot(idx < 0 || flag >= 1u);
            if (ball_valid != ~0ull) continue;      // some predecessor unpublished
            u64 ball_incl = __ballot(idx >= 0 && flag == 2u);
            int val = (idx >= 0) ? (int)(unsigned)(st >> 32) : 0;
            if (ball_incl) {
                int c = __ffsll((long long)ball_incl) - 1;  // closest inclusive
                int contrib = (tid <= c) ? val : 0;
                for (int o = 1; o < 64; o <<= 1) contrib += __shfl_xor(contrib, o);
                prefix += contrib;
                break;
            } else {                                 // window all aggregates
                int contrib = val;
                for (int o = 1; o < 64; o <<= 1) contrib += __shfl_xor(contrib, o);
                prefix += contrib;
                j -= 64;
                if (j < 0) break;                    // unreachable (tile0 flag=2)
            }
        }
        if (tid == 0) {
            s_prefix = prefix;
            u64 pub = ((u64)(unsigned)(prefix + local_total) << 32) | 2u;
            __hip_atomic_store(&tstate[tile], pub, __ATOMIC_RELEASE, __HIP_MEMORY_SCOPE_AGENT);
        }
    }
    __syncthreads();
    int run = s_prefix + incl - orig;               // exclusive
    if (gid < total) start[gid] = run;
    if (gid == 0) start[total] = grand_total;
}

// Pass 2a (slot2, r10): compute records once AND bin them by slot-range.
// Slots are a permutation of [0,2E) -> bin b holds exactly the records with
// slot in [b*SL,(b+1)*SL); placement within a bin via LDS histogram + 8
// global cursor atomics/WG (6K device RMWs total).
__global__ void slot2_kernel(const int* __restrict__ start,
                             const int* __restrict__ row, const int* __restrict__ col,
                             const float* __restrict__ w, const unsigned* __restrict__ ranks,
                             const float* __restrict__ dinv,
                             unsigned* __restrict__ cursor,
                             unsigned* __restrict__ bslot, u64* __restrict__ bpay,
                             int E, int N, int SL) {
    __shared__ unsigned hist[NXCD];
    __shared__ unsigned wbase[NXCD];
    if (threadIdx.x < NXCD) hist[threadIdx.x] = 0;
    __syncthreads();
    long long g  = (long long)blockIdx.x * 256 + threadIdx.x;
    long long e0 = g * 4;
    unsigned rslot[8]; u64 rpay[8]; unsigned rbin[8], rrank[8];
    int nrec = 0;
    if (e0 < E) {
        if (e0 + 4 <= E && (E & 3) == 0) {
            int q = (int)(e0 >> 2);
            int4   r4 = *(const int4*)(row + 4 * (size_t)q);
            int4   c4 = *(const int4*)(col + 4 * (size_t)q);
            float4 w4 = *(const float4*)(w + 4 * (size_t)q);
            uv4    p4 = __builtin_nontemporal_load((const uv4*)(ranks + e0));
            int rr[4] = {r4.x, r4.y, r4.z, r4.w};
            int cc[4] = {c4.x, c4.y, c4.z, c4.w};
            float ww[4] = {w4.x, w4.y, w4.z, w4.w};
            unsigned pk[4] = {p4.x, p4.y, p4.z, p4.w};
            #pragma unroll
            for (int k = 0; k < 4; ++k) {
                int ss = start[cc[k]] + (int)(pk[k] & 0xffffu);
                int st = start[N + rr[k]] + (int)(pk[k] >> 16);
                float wns = ww[k] * dinv[N + rr[k]];
                float wnt = ww[k] * dinv[cc[k]];
                rslot[nrec] = (unsigned)ss;
                rpay[nrec]  = ((u64)__float_as_uint(wns) << 32) | (unsigned)rr[k];
                ++nrec;
                rslot[nrec] = (unsigned)st;
                rpay[nrec]  = ((u64)__float_as_uint(wnt) << 32) | (unsigned)cc[k];
                ++nrec;
            }
        } else {
            for (long long e = e0; e < E && e < e0 + 4; ++e) {
                int r = row[e], c = col[e];
                float we = w[e];
                unsigned pk = ranks[e];
                int ss = start[c] + (int)(pk & 0xffffu);
                int st = start[N + r] + (int)(pk >> 16);
                float wns = we * dinv[N + r];
                float wnt = we * dinv[c];
                rslot[nrec] = (unsigned)ss;
                rpay[nrec]  = ((u64)__float_as_uint(wns) << 32) | (unsigned)r;
                ++nrec;
                rslot[nrec] = (unsigned)st;
                rpay[nrec]  = ((u64)__float_as_uint(wnt) << 32) | (unsigned)c;
                ++nrec;
            }
        }
        for (int j = 0; j < nrec; ++j) {
            rbin[j]  = rslot[j] / (unsigned)SL;
            rrank[j] = atomicAdd(&hist[rbin[j]], 1u);
        }
    }
    __syncthreads();
    if (threadIdx.x < NXCD)
        wbase[threadIdx.x] = atomicAdd(&cursor[threadIdx.x], hist[threadIdx.x]);
    __syncthreads();
    for (int j = 0; j < nrec; ++j) {
        unsigned pos = rbin[j] * (unsigned)SL + wbase[rbin[j]] + rrank[j];
        bslot[pos] = rslot[j];
        bpay[pos]  = rpay[j];
    }
}

// Pass 2b (fill2, r10): block rid=blockIdx&7 reads ONLY bin rid (sequential,
// exactly once) and scatter-writes into its own 1.6MB slot window -> the ~8
// payloads sharing a 64B line merge in ONE XCD's L2.
__global__ void fill2_kernel(const unsigned* __restrict__ bslot, const u64* __restrict__ bpay,
                             u64* __restrict__ edges, int E2, int SL) {
    int rid = blockIdx.x & 7;
    long long idx = ((long long)(blockIdx.x >> 3) * 256 + threadIdx.x) * 2;
    long long lo  = (long long)rid * SL;
    long long rem = (long long)E2 - lo;
    int cntb = rem < 0 ? 0 : (rem > SL ? SL : (int)rem);
    if (idx >= cntb) return;
    long long p = lo + idx;
    if (idx + 2 <= cntb) {
        u64   s2 = __builtin_nontemporal_load((const u64*)(bslot + p));
        u64v2 y2 = __builtin_nontemporal_load((const u64v2*)(bpay + p));
        unsigned s0 = (unsigned)(s2 & 0xffffffffu), s1 = (unsigned)(s2 >> 32);
        edges[s0] = y2[0];
        edges[s1] = y2[1];
    } else {
        edges[bslot[p]] = __builtin_nontemporal_load(bpay + p);
    }
}

// ---------------------------------------------------------------------------
// Pull kernels (r7 half-wave, best measured): wave per bucket; HALF-WAVE per
// edge (bf16 row = 256B = 32 lanes x ushort4). Main loop 8 edges/iter.
__global__ void pull1_kernel(const int* __restrict__ start, const int2* __restrict__ edges,
                             const float* __restrict__ dinv,
                             const u16* __restrict__ xb_s, const u16* __restrict__ xb_t,
                             const float* __restrict__ x_s, const float* __restrict__ x_t,
                             u16* __restrict__ ab_s, u16* __restrict__ ab_t, int N) {
    int wid0 = (int)(((long long)blockIdx.x * blockDim.x + threadIdx.x) >> 6);
    int wid = __builtin_amdgcn_readfirstlane(wid0);
    int lane = threadIdx.x & 63;
    int half = lane >> 5, hl = lane & 31;
    if (wid >= 2 * N) return;
    const u16* xb; const float* x; u16* ab; int i, o;
    if (wid < N) { i = wid;     o = N; xb = xb_s; x = x_s; ab = ab_s; }
    else         { i = wid - N; o = 0; xb = xb_t; x = x_t; ab = ab_t; }
    int s0 = start[wid], s1 = start[wid + 1];
    float a0 = 0.f, a1 = 0.f, a2 = 0.f, a3 = 0.f;
    int k = s0;
    for (; k + 8 <= s1; k += 8) {
        int b = k + 4 * half;
        int2 p0 = edges[b], p1 = edges[b + 1], p2 = edges[b + 2], p3 = edges[b + 3];
        ushort4 v0 = *(const ushort4*)(xb + (size_t)p0.x * D + hl * 4);
        ushort4 v1 = *(const ushort4*)(xb + (size_t)p1.x * D + hl * 4);
        ushort4 v2 = *(const ushort4*)(xb + (size_t)p2.x * D + hl * 4);
        ushort4 v3 = *(const ushort4*)(xb + (size_t)p3.x * D + hl * 4);
        float w0v = __int_as_float(p0.y), w1v = __int_as_float(p1.y);
        float w2v = __int_as_float(p2.y), w3v = __int_as_float(p3.y);
        a0 += w0v * bf2f(v0.x) + w1v * bf2f(v1.x) + w2v * bf2f(v2.x) + w3v * bf2f(v3.x);
        a1 += w0v * bf2f(v0.y) + w1v * bf2f(v1.y) + w2v * bf2f(v2.y) + w3v * bf2f(v3.y);
        a2 += w0v * bf2f(v0.z) + w1v * bf2f(v1.z) + w2v * bf2f(v2.z) + w3v * bf2f(v3.z);
        a3 += w0v * bf2f(v0.w) + w1v * bf2f(v1.w) + w2v * bf2f(v2.w) + w3v * bf2f(v3.w);
    }
    if (k + 4 <= s1) {
        int b = k + 2 * half;
        int2 p0 = edges[b], p1 = edges[b + 1];
        ushort4 v0 = *(const ushort4*)(xb + (size_t)p0.x * D + hl * 4);
        ushort4 v1 = *(const ushort4*)(xb + (size_t)p1.x * D + hl * 4);
        float w0v = __int_as_float(p0.y), w1v = __int_as_float(p1.y);
        a0 += w0v * bf2f(v0.x) + w1v * bf2f(v1.x);
        a1 += w0v * bf2f(v0.y) + w1v * bf2f(v1.y);
        a2 += w0v * bf2f(v0.z) + w1v * bf2f(v1.z);
        a3 += w0v * bf2f(v0.w) + w1v * bf2f(v1.w);
        k += 4;
    }
    for (; k < s1; ++k) {
        if (half == 0) {
            int2 p = edges[k];
            ushort4 v = *(const ushort4*)(xb + (size_t)p.x * D + hl * 4);
            float wv = __int_as_float(p.y);
            a0 += wv * bf2f(v.x); a1 += wv * bf2f(v.y);
            a2 += wv * bf2f(v.z); a3 += wv * bf2f(v.w);
        }
    }
    a0 += __shfl_xor(a0, 32); a1 += __shfl_xor(a1, 32);
    a2 += __shfl_xor(a2, 32); a3 += __shfl_xor(a3, 32);
    if (half == 0) {
        float sw = FILLV * dinv[o + i];
        float4 xv = *(const float4*)(x + (size_t)i * D + hl * 4);
        a0 += sw * xv.x; a1 += sw * xv.y; a2 += sw * xv.z; a3 += sw * xv.w;
        ushort4 ov;
        ov.x = f2bf(a0); ov.y = f2bf(a1); ov.z = f2bf(a2); ov.w = f2bf(a3);
        *(ushort4*)(ab + (size_t)i * D + hl * 4) = ov;
    }
}

// Hop-2 pull + fused epilogue: out_half = w0*x + w1*a + w2*(conv(a)).
__global__ void pull2_kernel(const int* __restrict__ start, const int2* __restrict__ edges,
                             const float* __restrict__ dinv,
                             const u16* __restrict__ ab_s, const u16* __restrict__ ab_t,
                             const float* __restrict__ x_s, const float* __restrict__ x_t,
                             float* __restrict__ out,
                             const float* __restrict__ w_s, const float* __restrict__ w_t, int N) {
    int wid0 = (int)(((long long)blockIdx.x * blockDim.x + threadIdx.x) >> 6);
    int wid = __builtin_amdgcn_readfirstlane(wid0);
    int lane = threadIdx.x & 63;
    int half = lane >> 5, hl = lane & 31;
    if (wid >= 2 * N) return;
    const u16* ab; const float* x; const float* wv3; int i, o, hoff;
    if (wid < N) { i = wid;     o = N; ab = ab_s; x = x_s; wv3 = w_s; hoff = 0; }
    else         { i = wid - N; o = 0; ab = ab_t; x = x_t; wv3 = w_t; hoff = D; }
    int s0 = start[wid], s1 = start[wid + 1];
    float a0 = 0.f, a1 = 0.f, a2 = 0.f, a3 = 0.f;
    int k = s0;
    for (; k + 8 <= s1; k += 8) {
        int b = k + 4 * half;
        int2 p0 = edges[b], p1 = edges[b + 1], p2 = edges[b + 2], p3 = edges[b + 3];
        ushort4 v0 = *(const ushort4*)(ab + (size_t)p0.x * D + hl * 4);
        ushort4 v1 = *(const ushort4*)(ab + (size_t)p1.x * D + hl * 4);
        ushort4 v2 = *(const ushort4*)(ab + (size_t)p2.x * D + hl * 4);
        ushort4 v3 = *(const ushort4*)(ab + (size_t)p3.x * D + hl * 4);
        float w0v = __int_as_float(p0.y), w1v = __int_as_float(p1.y);
        float w2v = __int_as_float(p2.y), w3v = __int_as_float(p3.y);
        a0 += w0v * bf2f(v0.x) + w1v * bf2f(v1.x) + w2v * bf2f(v2.x) + w3v * bf2f(v3.x);
        a1 += w0v * bf2f(v0.y) + w1v * bf2f(v1.y) + w2v * bf2f(v2.y) + w3v * bf2f(v3.y);
        a2 += w0v * bf2f(v0.z) + w1v * bf2f(v1.z) + w2v * bf2f(v2.z) + w3v * bf2f(v3.z);
        a3 += w0v * bf2f(v0.w) + w1v * bf2f(v1.w) + w2v * bf2f(v2.w) + w3v * bf2f(v3.w);
    }
    if (k + 4 <= s1) {
        int b = k + 2 * half;
        int2 p0 = edges[b], p1 = edges[b + 1];
        ushort4 v0 = *(const ushort4*)(ab + (size_t)p0.x * D + hl * 4);
        ushort4 v1 = *(const ushort4*)(ab + (size_t)p1.x * D + hl * 4);
        float w0v = __int_as_float(p0.y), w1v = __int_as_float(p1.y);
        a0 += w0v * bf2f(v0.x) + w1v * bf2f(v1.x);
        a1 += w0v * bf2f(v0.y) + w1v * bf2f(v1.y);
        a2 += w0v * bf2f(v0.z) + w1v * bf2f(v1.z);
        a3 += w0v * bf2f(v0.w) + w1v * bf2f(v1.w);
        k += 4;
    }
    for (; k < s1; ++k) {
        if (half == 0) {
            int2 p = edges[k];
            ushort4 v = *(const ushort4*)(ab + (size_t)p.x * D + hl * 4);
            float wv = __int_as_float(p.y);
            a0 += wv * bf2f(v.x); a1 += wv * bf2f(v.y);
            a2 += wv * bf2f(v.z); a3 += wv * bf2f(v.w);
        }
    }
    a0 += __shfl_xor(a0, 32); a1 += __shfl_xor(a1, 32);
    a2 += __shfl_xor(a2, 32); a3 += __shfl_xor(a3, 32);
    if (half == 0) {
        float sw = FILLV * dinv[o + i];
        ushort4 av = *(const ushort4*)(ab + (size_t)i * D + hl * 4);
        float b0 = bf2f(av.x), b1 = bf2f(av.y), b2 = bf2f(av.z), b3 = bf2f(av.w);
        a0 += sw * b0; a1 += sw * b1; a2 += sw * b2; a3 += sw * b3;
        float w0 = wv3[0], w1 = wv3[1], w2 = wv3[2];
        float4 xv = *(const float4*)(x + (size_t)i * D + hl * 4);
        float4 ov;
        ov.x = w0 * xv.x + w1 * b0 + w2 * a0;
        ov.y = w0 * xv.y + w1 * b1 + w2 * a1;
        ov.z = w0 * xv.z + w1 * b2 + w2 * a2;
        ov.w = w0 * xv.w + w1 * b3 + w2 * a3;
        *(float4*)(out + (size_t)i * 2 * D + hoff + hl * 4) = ov;
    }
}

// ---------------------------------------------------------------------------
extern "C" void kernel_launch(void* const* d_in, const int* in_sizes, int n_in,
                              void* d_out, int out_size, void* d_ws, size_t ws_size,
                              hipStream_t stream) {
    const float* x_s = (const float*)d_in[0];
    const float* x_t = (const float*)d_in[1];
    const int*   ei  = (const int*)d_in[2];
    const float* ew  = (const float*)d_in[3];
    const float* w_s = (const float*)d_in[4];
    const float* w_t = (const float*)d_in[5];
    const int N = in_sizes[0] / D;
    const int E = in_sizes[3];
    const int* row = ei;
    const int* col = ei + E;

    const int total = 2 * N;
    const int nTiles = (total + 255) / 256;        // <= 512
    const int SL = ((2 * E + NXCD - 1) / NXCD + 7) & ~7;   // bin/range size

    // Workspace (d_ws): [dinv 2N][start 2N+2][align]
    // [edges 2E int2 (64B-aligned)] [xb_s ND u16][xb_t ND u16][ab_s][ab_t]
    // cnt32 (2N u32) + cursor (8 u32) + tstate (u64[512]) alias ab_s:
    // dead before pull1.
    float* f      = (float*)d_ws;
    float* dinv   = f;                              // 2N
    int*   start  = (int*)(f + (size_t)total);      // 2N+2
    char*  pc     = (char*)(start + total + 2);
    pc = (char*)(((size_t)pc + 255) & ~(size_t)255);
    u64*   edges  = (u64*)pc;                       // 2E int2, 64B-aligned
    u16*   xb_s   = (u16*)(edges + 2 * (size_t)E);
    u16*   xb_t   = xb_s + (size_t)N * D;
    u16*   ab_s   = xb_t + (size_t)N * D;
    u16*   ab_t   = ab_s + (size_t)N * D;
    unsigned* cnt32  = (unsigned*)ab_s;             // 2N, dead before pull1
    unsigned* cursor = cnt32 + (size_t)total;       // 8 bin cursors
    u64*      tstate = (u64*)(cursor + NXCD);       // 512 scan tile states

    // d_out scratch (dead until pull2 writes): ranks u32[E], then binned
    // records bslot u32[8SL] + bpay u64[8SL] (16B-aligned). ~22.4MB total.
    unsigned* ranks = (unsigned*)d_out;
    char* po = (char*)d_out + (((size_t)E * 4 + 15) & ~(size_t)15);
    unsigned* bslot = (unsigned*)po;                           // 8SL u32
    u64*      bpay  = (u64*)(bslot + (size_t)NXCD * SL);       // 8SL u64
    float* out = (float*)d_out;

    hipMemsetAsync(cnt32, 0,
                   ((size_t)total + NXCD) * sizeof(unsigned) + 512 * sizeof(u64),
                   stream);

    long long nd = (long long)N * D;
    int blkC = (int)((nd / 2 + 255) / 256);
    int nEB  = (E + EPT * 256 - 1) / (EPT * 256);
    cnt_tobf_kernel<<<nEB + blkC, 256, 0, stream>>>(row, col, ew, cnt32, ranks,
                                                    x_s, x_t, xb_s, xb_t,
                                                    E, N, nEB, nd);

    scanF_kernel<<<nTiles, 256, 0, stream>>>(cnt32, dinv, tstate, start,
                                             total, 2 * E);

    int blkS = (E + 1023) / 1024;                   // 4 edges/thread
    slot2_kernel<<<blkS, 256, 0, stream>>>(start, row, col, ew, ranks, dinv,
                                           cursor, bslot, bpay, E, N, SL);

    int blkF = 8 * ((SL + 511) / 512);              // 2 records/thread per bin
    fill2_kernel<<<blkF, 256, 0, stream>>>(bslot, bpay, edges, 2 * E, SL);

    long long pull_threads = (long long)total * 64;
    int blkP = (int)((pull_threads + 255) / 256);
    pull1_kernel<<<blkP, 256, 0, stream>>>(start, (const int2*)edges, dinv, xb_s, xb_t,
                                           x_s, x_t, ab_s, ab_t, N);
    pull2_kernel<<<blkP, 256, 0, stream>>>(start, (const int2*)edges, dinv, ab_s, ab_t,
                                           x_s, x_t, out, w_s, w_t, N);
}